// Round 8
// baseline (185.871 us; speedup 1.0000x reference)
//
#include <hip/hip_runtime.h>
#include <float.h>
#include <math.h>

// Problem constants (reference: x shape (2,1024,32000) fp32, dim=-1, alpha=1.5)
#define D_DIM   32000
#define NT      512                         // 8 waves; 2 blocks/CU (VGPR-bound)
#define CHUNKS  (D_DIM / 4)                 // 8000 float4 chunks per row
#define KITER   ((CHUNKS + NT - 1) / NT)    // 16 chunks per thread (64 VGPR of data)
#define NWAVES  (NT / 64)                   // 8
#define CAPW    512                         // pool capacity per wave (exact active set ~50)

typedef float f32x4 __attribute__((ext_vector_type(4)));
typedef unsigned long long ull;

__device__ __forceinline__ float waveReduceSum(float v) {
#pragma unroll
    for (int m = 32; m >= 1; m >>= 1) v += __shfl_xor(v, m, 64);
    return v;
}

__device__ __forceinline__ float waveReduceMax(float v) {
#pragma unroll
    for (int m = 32; m >= 1; m >>= 1) v = fmaxf(v, __shfl_xor(v, m, 64));
    return v;
}

// Bit-level finite scrub: maps NaN and +/-inf to -FLT_MAX. Integer-domain so
// -ffinite-math-only cannot fold it away.
__device__ __forceinline__ float scrub_finite(float v) {
    const unsigned u = __float_as_uint(v);
    if ((u & 0x7f800000u) == 0x7f800000u) return -FLT_MAX;
    return v;
}

__device__ __forceinline__ float4 ldg4(const float4* __restrict__ p, int c) {
    if (c < CHUNKS) return p[c];
    float4 r; r.x = r.y = r.z = r.w = -FLT_MAX;   // pad; *0.5 stays hugely negative
    return r;
}

// Register-resident fused kernel (R8 redesign):
//  - NT=512 -> the row is 16 float4 = 64 VGPR/thread. Load once, keep it.
//  - Exact block max FIRST (one register tree + ONE shuffle-reduce per row),
//    then one-pass admission at the EXACT threshold max-1 into per-wave LDS
//    pools. Kills R7's running-max/lag-pipeline/eviction machinery (it only
//    existed because max was unknown mid-stream).
//  - Wave 0 bisects over the 8 pools barrier-free (identical algorithm and
//    scan discipline as the verified R7 kernel), broadcasts via LDS.
//  - Epilogue computes log(p/sum) FROM REGISTERS (no L3 re-read at all),
//    nt-stores the output (keeps x L3-resident across bench iterations).
__global__ __launch_bounds__(NT, 2)
void entmax_log_fused(const float* __restrict__ x, float* __restrict__ out, int rows)
{
    const int row = blockIdx.x;
    if (row >= rows) return;
    const size_t base = (size_t)row * D_DIM;
    const float4* __restrict__ xr4 = reinterpret_cast<const float4*>(x + base);
    float* __restrict__ orow = out + base;

    __shared__ __align__(16) float s_pool[NWAVES * CAPW];   // 16 KB
    __shared__ float s_red[NWAVES];
    __shared__ int   s_cnt[NWAVES];
    __shared__ int   s_flag;
    __shared__ float2 s_ts;

    const int lane = threadIdx.x & 63;
    const int wv   = threadIdx.x >> 6;
    float* __restrict__ wpool = s_pool + wv * CAPW;
    const ull lmask = (1ull << lane) - 1ull;

    if (threadIdx.x == 0) s_flag = 0;

    // ---- load entire row into registers (16 loads in flight, scaled by 0.5) ----
    float4 z[KITER];
#pragma unroll
    for (int k = 0; k < KITER; ++k) {
        const float4 v = ldg4(xr4, threadIdx.x + k * NT);
        z[k].x = v.x * 0.5f; z[k].y = v.y * 0.5f;
        z[k].z = v.z * 0.5f; z[k].w = v.w * 0.5f;
    }

    // ---- exact block max: register tree -> one wave reduce -> LDS ----
    float m = -FLT_MAX;
#pragma unroll
    for (int k = 0; k < KITER; ++k)
        m = fmaxf(m, fmaxf(fmaxf(z[k].x, z[k].y), fmaxf(z[k].z, z[k].w)));
    m = waveReduceMax(m);
    if (lane == 0) s_red[wv] = m;
    __syncthreads();
    float max_val = s_red[0];
#pragma unroll
    for (int w = 1; w < NWAVES; ++w) max_val = fmaxf(max_val, s_red[w]);

    const float tau_lo0 = max_val - 1.0f;                   // gp(1) = 1
    const float tau_hi = max_val - 0.005590169943749474f;   // (1/32000)^0.5
    const float thr = tau_lo0;

    // ---- one-pass admission at the exact threshold (ballot + rank) ----
    // Pool = exactly {z > max-1}, the true active superset of every f(tau)
    // evaluated at tau >= max-1. Deterministic order: (k, component, lane).
    int n = 0;   // wave-uniform running count
#define ADMIT(val)                                                        \
    do {                                                                  \
        const float zz = (val);                                           \
        const ull mk = __ballot(zz > thr);                                \
        if (zz > thr) {                                                   \
            const int r = __popcll(mk & lmask);                           \
            if (n + r < CAPW) wpool[n + r] = zz;                          \
        }                                                                 \
        n += __popcll(mk);                                                \
    } while (0)
#pragma unroll
    for (int k = 0; k < KITER; ++k) {
        ADMIT(z[k].x); ADMIT(z[k].y); ADMIT(z[k].z); ADMIT(z[k].w);
    }
#undef ADMIT
    if (lane == 0) {
        s_cnt[wv] = (n <= CAPW) ? n : 0;
        if (n > CAPW) s_flag = 1;   // P ~ 1e-10 on N(0,1) rows; fallback below
    }
    __syncthreads();
    const int flag = s_flag;

    if (!flag) {
        // ---- wave-0-only barrier-free bisection over all 8 pools ----
        if (wv == 0) {
            float tau_lo = tau_lo0;
            float fl = 0.0f;
            for (int w = 0; w < NWAVES; ++w) {
                const float* __restrict__ pp = s_pool + w * CAPW;
                const int nw = s_cnt[w];
                for (int i = lane; i < nw; i += 64) {
                    const float t = fmaxf(pp[i] - tau_lo, 0.0f);
                    fl = fmaf(t, t, fl);
                }
            }
            fl = waveReduceSum(fl) - 1.0f;

            float dm = tau_hi - tau_lo;
            float tau_m = tau_lo;
            float s_final = 1.0f;
            for (int it = 0; it < 100; ++it) {
                dm *= 0.5f;
                tau_m = tau_lo + dm;
                const bool fixed = (tau_m == tau_lo);   // wave-uniform
                float a = 0.0f;
                for (int w = 0; w < NWAVES; ++w) {
                    const float* __restrict__ pp = s_pool + w * CAPW;
                    const int nw = s_cnt[w];
                    for (int i = lane; i < nw; i += 64) {
                        const float t = fmaxf(pp[i] - tau_m, 0.0f);
                        a = fmaf(t, t, a);
                    }
                }
                a = waveReduceSum(a);
                s_final = a;
                if ((a - 1.0f) * fl >= 0.0f) tau_lo = tau_m;
                if (fixed) break;
            }
            if (lane == 0) { s_ts.x = tau_m; s_ts.y = s_final; }
        }
        __syncthreads();   // bisection result published
    } else {
        // ---- fallback (unreachable on sane data): block bisect FROM REGS ----
        float tau_lo = tau_lo0;
#define FACC(val, tauv, acc)                                              \
    do { const float t = fmaxf((val) - (tauv), 0.0f); acc = fmaf(t, t, acc); } while (0)
        float acc = 0.0f;
#pragma unroll
        for (int k = 0; k < KITER; ++k) {
            FACC(z[k].x, tau_lo, acc); FACC(z[k].y, tau_lo, acc);
            FACC(z[k].z, tau_lo, acc); FACC(z[k].w, tau_lo, acc);
        }
        acc = waveReduceSum(acc);
        if (lane == 0) s_red[wv] = acc;
        __syncthreads();
        float f_lo = -1.0f;
#pragma unroll
        for (int w = 0; w < NWAVES; ++w) f_lo += s_red[w];
        __syncthreads();

        float dm = tau_hi - tau_lo;
        float tau_m = tau_lo;
        float s_final = 1.0f;
        for (int it = 0; it < 100; ++it) {
            dm *= 0.5f;
            tau_m = tau_lo + dm;
            const bool fixed = (tau_m == tau_lo);
            float a = 0.0f;
#pragma unroll
            for (int k = 0; k < KITER; ++k) {
                FACC(z[k].x, tau_m, a); FACC(z[k].y, tau_m, a);
                FACC(z[k].z, tau_m, a); FACC(z[k].w, tau_m, a);
            }
            a = waveReduceSum(a);
            if (lane == 0) s_red[wv] = a;
            __syncthreads();
            float s = 0.0f;
#pragma unroll
            for (int w = 0; w < NWAVES; ++w) s += s_red[w];
            __syncthreads();
            s_final = s;
            if ((s - 1.0f) * f_lo >= 0.0f) tau_lo = tau_m;
            if (fixed) break;
        }
#undef FACC
        if (threadIdx.x == 0) { s_ts.x = tau_m; s_ts.y = s_final; }
        __syncthreads();
    }

    // ---- epilogue FROM REGISTERS -> log(p/sum), nt-store ----
    // Verified numeric path: floor p before log (DAZ-safe), bit-scrub residual
    // inf/NaN. No memory reads here at all.
    const float tau_m = s_ts.x;
    const float inv_s = 1.0f / s_ts.y;
#pragma unroll
    for (int k = 0; k < KITER; ++k) {
        const int c = threadIdx.x + k * NT;
        if (c < CHUNKS) {
            f32x4 o;
            {
                const float t = fmaxf(z[k].x - tau_m, 0.0f);
                o.x = scrub_finite(__logf(fmaxf(t * t, 1e-35f) * inv_s));
            }
            {
                const float t = fmaxf(z[k].y - tau_m, 0.0f);
                o.y = scrub_finite(__logf(fmaxf(t * t, 1e-35f) * inv_s));
            }
            {
                const float t = fmaxf(z[k].z - tau_m, 0.0f);
                o.z = scrub_finite(__logf(fmaxf(t * t, 1e-35f) * inv_s));
            }
            {
                const float t = fmaxf(z[k].w - tau_m, 0.0f);
                o.w = scrub_finite(__logf(fmaxf(t * t, 1e-35f) * inv_s));
            }
            __builtin_nontemporal_store(o, reinterpret_cast<f32x4*>(orow) + c);
        }
    }
}

extern "C" void kernel_launch(void* const* d_in, const int* in_sizes, int n_in,
                              void* d_out, int out_size, void* d_ws, size_t ws_size,
                              hipStream_t stream) {
    const float* x = (const float*)d_in[0];
    float* out = (float*)d_out;
    const int rows = in_sizes[0] / D_DIM;
    entmax_log_fused<<<dim3(rows), dim3(NT), 0, stream>>>(x, out, rows);
}

// Round 9
// 145.299 us; speedup vs baseline: 1.2792x; 1.2792x over previous
//
#include <hip/hip_runtime.h>
#include <float.h>
#include <math.h>

// Problem constants (reference: x shape (2,1024,32000) fp32, dim=-1, alpha=1.5)
// R9: all hot-loop math in v-space (v = 2z = x*(alpha-1)*2 = x). Since 0.5 is a
// power of two, z = 0.5v is exact; tau = 0.5u exact; and the normalized output
// p = max(z-tau,0)^2 / sum == max(v-u,0)^2 / sum_v  (the 0.25 cancels exactly).
// So the kernel never multiplies by 0.5 at all.
#define D_DIM   32000
#define NT      256                         // 4 waves -> 8 blocks/CU
#define CHUNKS  (D_DIM / 4)                 // 8000 float4 chunks per row
#define KITER   ((CHUNKS + NT - 1) / NT)    // 32 chunks per thread
#define NG4     (KITER / 4)                 // 8 four-chunk groups (16 elems each)
#define NWAVES  (NT / 64)                   // 4
#define CAPW    1200                        // per-wave pool capacity (4800 B)

typedef float f32x4 __attribute__((ext_vector_type(4)));
typedef unsigned long long ull;

__device__ __forceinline__ float waveReduceSum(float v) {
#pragma unroll
    for (int m = 32; m >= 1; m >>= 1) v += __shfl_xor(v, m, 64);
    return v;
}

__device__ __forceinline__ float waveReduceMax(float v) {
#pragma unroll
    for (int m = 32; m >= 1; m >>= 1) v = fmaxf(v, __shfl_xor(v, m, 64));
    return v;
}

// Bit-level finite scrub: maps NaN and +/-inf to -FLT_MAX. Integer-domain so
// -ffinite-math-only cannot fold it away.
__device__ __forceinline__ float scrub_finite(float v) {
    const unsigned u = __float_as_uint(v);
    if ((u & 0x7f800000u) == 0x7f800000u) return -FLT_MAX;
    return v;
}

__device__ __forceinline__ float4 ldg4(const float4* __restrict__ p, int c) {
    if (c < CHUNKS) return p[c];
    float4 r; r.x = r.y = r.z = r.w = -FLT_MAX;   // pad stays hugely negative
    return r;
}

// Fused kernel (R7 skeleton, best-known structure at 146us):
//  pass 1 : stream row raw (no scale). Admission thr = fmax(runL, lagWaveM) - 2
//           (v-space: z > max_z-1  <=>  v > max_v-2). Lag-pipelined wave max
//           keeps the 6-deep shuffle reduce off the per-group critical path.
//           Ballot+rank append into per-wave LDS pool; wave-cooperative
//           eviction (entries <= thr contribute exactly 0 forever) on overflow.
//  bisect : final eviction at max_v-2, wave 0 scans all 4 pools barrier-free,
//           f(u) = sum max(v-u,0)^2 vs target 4.0.
//  epilog : re-read row (L3-hot) -> log(max(v-u,0)^2 * inv_sv), nt-store.
__global__ __launch_bounds__(NT, 8)
void entmax_log_fused(const float* __restrict__ x, float* __restrict__ out, int rows)
{
    const int row = blockIdx.x;
    if (row >= rows) return;
    const size_t base = (size_t)row * D_DIM;
    const float4* __restrict__ xr4 = reinterpret_cast<const float4*>(x + base);
    float* __restrict__ orow = out + base;

    __shared__ __align__(16) float s_pool[NWAVES * CAPW];   // 19200 B
    __shared__ float s_red[NWAVES];
    __shared__ int   s_cnt[NWAVES];
    __shared__ int   s_flag;
    __shared__ float2 s_ts;

    const int lane = threadIdx.x & 63;
    const int wv   = threadIdx.x >> 6;
    float* __restrict__ wpool = s_pool + wv * CAPW;
    const ull lmask = (1ull << lane) - 1ull;

    if (threadIdx.x == 0) s_flag = 0;
    __syncthreads();

    // ---- pass 1: stream row; lag wave max + per-lane max admission ----
    float runL  = -FLT_MAX;   // per-lane running max (raw v)
    float waveM = -FLT_MAX;   // wave max through 2 groups ago (uniform)
    float pendR = -FLT_MAX;   // in-flight reduce result
    int n = 0;                // wave-uniform pool count
    bool ovf = false;

    float4 cur[4], nxt[4];
#pragma unroll
    for (int j = 0; j < 4; ++j) cur[j] = ldg4(xr4, threadIdx.x + j * NT);

    for (int g = 0; g < NG4; ++g) {
        if (g + 1 < NG4) {
#pragma unroll
            for (int j = 0; j < 4; ++j)
                nxt[j] = ldg4(xr4, threadIdx.x + ((g + 1) * 4 + j) * NT);
        }
        float z[16];
#pragma unroll
        for (int j = 0; j < 4; ++j) {
            z[4 * j + 0] = cur[j].x; z[4 * j + 1] = cur[j].y;
            z[4 * j + 2] = cur[j].z; z[4 * j + 3] = cur[j].w;
        }
        float cm = z[0];
#pragma unroll
        for (int i = 1; i < 16; ++i) cm = fmaxf(cm, z[i]);
        runL = fmaxf(runL, cm);
        if ((g & 1) == 0) {                   // every 8 chunks (same as R7 cadence)
            waveM = fmaxf(waveM, pendR);      // consume reduce launched 2 groups ago
            pendR = waveReduceMax(runL);      // launch new; 2 group-times to finish
        }

        float thrL = fmaxf(runL, waveM) - 2.0f;   // per-lane lower bound of max_v-2
        ull msk[16];
        int tot = 0;
#pragma unroll
        for (int j = 0; j < 16; ++j) {
            msk[j] = __ballot(z[j] > thrL);
            tot += __popcll(msk[j]);
        }
        if (tot) {
            if (n + tot > CAPW) {
                // fresh uniform wave max; evict dead entries (<= wfresh-2).
                const float wfresh = waveReduceMax(runL);
                waveM = fmaxf(waveM, wfresh);
                const float thrW = wfresh - 2.0f;
                int nn = 0;
                for (int i = 0; i < n; i += 64) {
                    const float v = (i + lane < n) ? wpool[i + lane] : -FLT_MAX;
                    const ull km = __ballot(v > thrW);
                    const int r = __popcll(km & lmask);
                    if (v > thrW) wpool[nn + r] = v;   // dest <= src: in-place safe
                    nn += __popcll(km);
                }
                n = nn;
                // re-admit this group against the tightened threshold
                thrL = fmaxf(runL, waveM) - 2.0f;
                tot = 0;
#pragma unroll
                for (int j = 0; j < 16; ++j) {
                    msk[j] = __ballot(z[j] > thrL);
                    tot += __popcll(msk[j]);
                }
            }
            if (n + tot > CAPW) {
                ovf = true;          // adversarial/degenerate rows only
            } else {
#pragma unroll
                for (int j = 0; j < 16; ++j) {
                    if (z[j] > thrL) {
                        const int r = __popcll(msk[j] & lmask);
                        wpool[n + r] = z[j];
                    }
                    n += __popcll(msk[j]);
                }
            }
        }
#pragma unroll
        for (int j = 0; j < 4; ++j) cur[j] = nxt[j];
    }
    if (ovf && lane == 0) s_flag = 1;   // benign race across waves

    if (lane == 0) s_red[wv] = waveReduceMax(runL);   // exact final wave max
    __syncthreads();
    const float max_val = fmaxf(fmaxf(s_red[0], s_red[1]), fmaxf(s_red[2], s_red[3]));
    const int flag = s_flag;
    __syncthreads();                     // s_red is reused below

    // v-space bounds: u = 2*tau. z-space [max_z-1, max_z-(1/d)^0.5] doubles.
    const float u_lo0 = max_val - 2.0f;
    const float u_hi  = max_val - 0.011180339887498949f;   // 2*(1/32000)^0.5

    if (!flag) {
        // ---- final eviction at thr = max_v-2 (block-uniform): pools shrink
        // to the true active superset (~600/row). Wave-local, deterministic. ----
        {
            int nn = 0;
            for (int i = 0; i < n; i += 64) {
                const float v = (i + lane < n) ? wpool[i + lane] : -FLT_MAX;
                const ull km = __ballot(v > u_lo0);
                const int r = __popcll(km & lmask);
                if (v > u_lo0) wpool[nn + r] = v;
                nn += __popcll(km);
            }
            if (lane == 0) s_cnt[wv] = nn;
        }
        __syncthreads();

        // ---- wave-0-only barrier-free bisection over all 4 pools ----
        // f(u) = sum max(v-u,0)^2, root at f == 4.0 (== sum p_z = 1).
        if (wv == 0) {
            const int n0 = s_cnt[0], n1 = s_cnt[1], n2 = s_cnt[2], n3 = s_cnt[3];

#define POOL_SCAN(uv, acc)                                                     \
            do {                                                               \
                const float* __restrict__ pp0 = s_pool;                        \
                for (int i = lane; i < n0; i += 64) {                          \
                    const float t = fmaxf(pp0[i] - (uv), 0.0f);                \
                    acc = fmaf(t, t, acc);                                     \
                }                                                              \
                const float* __restrict__ pp1 = s_pool + CAPW;                 \
                for (int i = lane; i < n1; i += 64) {                          \
                    const float t = fmaxf(pp1[i] - (uv), 0.0f);                \
                    acc = fmaf(t, t, acc);                                     \
                }                                                              \
                const float* __restrict__ pp2 = s_pool + 2 * CAPW;             \
                for (int i = lane; i < n2; i += 64) {                          \
                    const float t = fmaxf(pp2[i] - (uv), 0.0f);                \
                    acc = fmaf(t, t, acc);                                     \
                }                                                              \
                const float* __restrict__ pp3 = s_pool + 3 * CAPW;             \
                for (int i = lane; i < n3; i += 64) {                          \
                    const float t = fmaxf(pp3[i] - (uv), 0.0f);                \
                    acc = fmaf(t, t, acc);                                     \
                }                                                              \
            } while (0)

            float u_lo = u_lo0;
            float fl = 0.0f;
            POOL_SCAN(u_lo, fl);
            fl = waveReduceSum(fl) - 4.0f;

            float dm = u_hi - u_lo;
            float u_m = u_lo;
            float s_v = 4.0f;
            for (int it = 0; it < 100; ++it) {
                dm *= 0.5f;
                u_m = u_lo + dm;
                const bool fixed = (u_m == u_lo);   // wave-uniform
                float a = 0.0f;
                POOL_SCAN(u_m, a);
                a = waveReduceSum(a);
                s_v = a;
                if ((a - 4.0f) * fl >= 0.0f) u_lo = u_m;
                if (fixed) break;
            }
#undef POOL_SCAN
            if (lane == 0) { s_ts.x = u_m; s_ts.y = s_v; }
        }
        __syncthreads();   // bisection result published
    } else {
        // ---- fallback (degenerate rows only): stream row per iteration ----
        float u_lo = u_lo0;
        float acc = 0.0f;
        for (int k = 0; k < KITER; ++k) {
            const int c = threadIdx.x + k * NT;
            if (c < CHUNKS) {
                const float4 v = xr4[c];
                float t;
                t = fmaxf(v.x - u_lo, 0.0f); acc = fmaf(t, t, acc);
                t = fmaxf(v.y - u_lo, 0.0f); acc = fmaf(t, t, acc);
                t = fmaxf(v.z - u_lo, 0.0f); acc = fmaf(t, t, acc);
                t = fmaxf(v.w - u_lo, 0.0f); acc = fmaf(t, t, acc);
            }
        }
        acc = waveReduceSum(acc);
        if (lane == 0) s_red[wv] = acc;
        __syncthreads();
        const float f_lo = (s_red[0] + s_red[1] + s_red[2] + s_red[3]) - 4.0f;
        __syncthreads();

        float dm = u_hi - u_lo;
        float u_m = u_lo;
        float s_v = 4.0f;
        for (int it = 0; it < 100; ++it) {
            dm *= 0.5f;
            u_m = u_lo + dm;
            const bool fixed = (u_m == u_lo);
            float a = 0.0f;
            for (int k = 0; k < KITER; ++k) {
                const int c = threadIdx.x + k * NT;
                if (c < CHUNKS) {
                    const float4 v = xr4[c];
                    float t;
                    t = fmaxf(v.x - u_m, 0.0f); a = fmaf(t, t, a);
                    t = fmaxf(v.y - u_m, 0.0f); a = fmaf(t, t, a);
                    t = fmaxf(v.z - u_m, 0.0f); a = fmaf(t, t, a);
                    t = fmaxf(v.w - u_m, 0.0f); a = fmaf(t, t, a);
                }
            }
            a = waveReduceSum(a);
            if (lane == 0) s_red[wv] = a;
            __syncthreads();
            const float s = s_red[0] + s_red[1] + s_red[2] + s_red[3];
            __syncthreads();
            s_v = s;
            if ((s - 4.0f) * f_lo >= 0.0f) u_lo = u_m;
            if (fixed) break;
        }
        if (threadIdx.x == 0) { s_ts.x = u_m; s_ts.y = s_v; }
        __syncthreads();
    }

    // ---- epilogue: re-read row (L3-hot) -> log((v-u)^2 / s_v), nt-store ----
    // p = max(v-u,0)^2 * inv_sv is EXACTLY the z-space normalized probability
    // (0.25 cancels). Floor before log (DAZ-safe), bit-scrub residual inf/NaN.
    const float u_m = s_ts.x;
    const float inv_sv = 1.0f / s_ts.y;
    for (int k = 0; k < KITER; ++k) {
        const int c = threadIdx.x + k * NT;
        if (c < CHUNKS) {
            const float4 v = xr4[c];
            f32x4 o;
            {
                const float t = fmaxf(v.x - u_m, 0.0f);
                o.x = scrub_finite(__logf(fmaxf(t * t, 1e-35f) * inv_sv));
            }
            {
                const float t = fmaxf(v.y - u_m, 0.0f);
                o.y = scrub_finite(__logf(fmaxf(t * t, 1e-35f) * inv_sv));
            }
            {
                const float t = fmaxf(v.z - u_m, 0.0f);
                o.z = scrub_finite(__logf(fmaxf(t * t, 1e-35f) * inv_sv));
            }
            {
                const float t = fmaxf(v.w - u_m, 0.0f);
                o.w = scrub_finite(__logf(fmaxf(t * t, 1e-35f) * inv_sv));
            }
            __builtin_nontemporal_store(o, reinterpret_cast<f32x4*>(orow) + c);
        }
    }
}

extern "C" void kernel_launch(void* const* d_in, const int* in_sizes, int n_in,
                              void* d_out, int out_size, void* d_ws, size_t ws_size,
                              hipStream_t stream) {
    const float* x = (const float*)d_in[0];
    float* out = (float*)d_out;
    const int rows = in_sizes[0] / D_DIM;
    entmax_log_fused<<<dim3(rows), dim3(NT), 0, stream>>>(x, out, rows);
}

// Round 10
// 127.594 us; speedup vs baseline: 1.4567x; 1.1388x over previous
//
#include <hip/hip_runtime.h>
#include <float.h>
#include <math.h>

// Problem constants (reference: x shape (2,1024,32000) fp32, dim=-1, alpha=1.5)
// All hot-loop math in v-space (v = 2z = x). Since 0.5 is a power of two,
// z = 0.5v is exact; tau = 0.5u exact; p = max(z-tau,0)^2 / sum_z ==
// max(v-u,0)^2 / sum_v (the 0.25 cancels exactly). No scale multiply anywhere.
#define D_DIM   32000
#define NT      256                         // 4 waves -> 8 blocks/CU
#define CHUNKS  (D_DIM / 4)                 // 8000 float4 chunks per row
#define KITER   ((CHUNKS + NT - 1) / NT)    // 32 chunks per thread
#define NG4     (KITER / 4)                 // 8 four-chunk groups (16 elems each)
#define NWAVES  (NT / 64)                   // 4
#define CAPW    1200                        // per-wave pool capacity (4800 B)

typedef float f32x4 __attribute__((ext_vector_type(4)));
typedef unsigned long long ull;

__device__ __forceinline__ float waveReduceSum(float v) {
#pragma unroll
    for (int m = 32; m >= 1; m >>= 1) v += __shfl_xor(v, m, 64);
    return v;
}

__device__ __forceinline__ float waveReduceMax(float v) {
#pragma unroll
    for (int m = 32; m >= 1; m >>= 1) v = fmaxf(v, __shfl_xor(v, m, 64));
    return v;
}

// Bit-level finite scrub: maps NaN and +/-inf to -FLT_MAX. Integer-domain so
// -ffinite-math-only cannot fold it away.
__device__ __forceinline__ float scrub_finite(float v) {
    const unsigned u = __float_as_uint(v);
    if ((u & 0x7f800000u) == 0x7f800000u) return -FLT_MAX;
    return v;
}

__device__ __forceinline__ float4 ldg4(const float4* __restrict__ p, int c) {
    if (c < CHUNKS) return p[c];
    float4 r; r.x = r.y = r.z = r.w = -FLT_MAX;   // pad stays hugely negative
    return r;
}

// Fused kernel (R7/R9 skeleton):
//  pass 1 : stream row raw. Admission thr = fmax(runL, lagWaveM) - 2 with
//           lag-pipelined wave max; ballot+rank append into per-wave LDS pool;
//           wave-cooperative eviction on overflow (entries <= thr contribute
//           exactly 0 to every f(u) at u >= max-2: eviction is exact).
//  solve  : final eviction at max-2, then wave 0 runs NEWTON on
//           f(u) = sum max(v-u,0)^2 (convex, decreasing): monotone
//           convergence from below, ~7 scans vs bisection's ~25 (R10: the
//           bisect dead-zone was a phase-locked serial latency chain).
//  epilog : nt-load re-read (last use of x: evict-first) -> log(t^2 * inv_sv),
//           nt-store. Verified numeric path: floor before log, bit-scrub.
__global__ __launch_bounds__(NT, 8)
void entmax_log_fused(const float* __restrict__ x, float* __restrict__ out, int rows)
{
    const int row = blockIdx.x;
    if (row >= rows) return;
    const size_t base = (size_t)row * D_DIM;
    const float4* __restrict__ xr4 = reinterpret_cast<const float4*>(x + base);
    float* __restrict__ orow = out + base;

    __shared__ __align__(16) float s_pool[NWAVES * CAPW];   // 19200 B
    __shared__ float s_red[NWAVES];
    __shared__ int   s_cnt[NWAVES];
    __shared__ int   s_flag;
    __shared__ float2 s_ts;

    const int lane = threadIdx.x & 63;
    const int wv   = threadIdx.x >> 6;
    float* __restrict__ wpool = s_pool + wv * CAPW;
    const ull lmask = (1ull << lane) - 1ull;

    if (threadIdx.x == 0) s_flag = 0;
    __syncthreads();

    // ---- pass 1: stream row; lag wave max + per-lane max admission ----
    float runL  = -FLT_MAX;   // per-lane running max (raw v)
    float waveM = -FLT_MAX;   // wave max through 2 groups ago (uniform)
    float pendR = -FLT_MAX;   // in-flight reduce result
    int n = 0;                // wave-uniform pool count
    bool ovf = false;

    float4 cur[4], nxt[4];
#pragma unroll
    for (int j = 0; j < 4; ++j) cur[j] = ldg4(xr4, threadIdx.x + j * NT);

    for (int g = 0; g < NG4; ++g) {
        if (g + 1 < NG4) {
#pragma unroll
            for (int j = 0; j < 4; ++j)
                nxt[j] = ldg4(xr4, threadIdx.x + ((g + 1) * 4 + j) * NT);
        }
        float z[16];
#pragma unroll
        for (int j = 0; j < 4; ++j) {
            z[4 * j + 0] = cur[j].x; z[4 * j + 1] = cur[j].y;
            z[4 * j + 2] = cur[j].z; z[4 * j + 3] = cur[j].w;
        }
        float cm = z[0];
#pragma unroll
        for (int i = 1; i < 16; ++i) cm = fmaxf(cm, z[i]);
        runL = fmaxf(runL, cm);
        if ((g & 1) == 0) {                   // every 8 chunks
            waveM = fmaxf(waveM, pendR);      // consume reduce from 2 groups ago
            pendR = waveReduceMax(runL);      // launch new; 2 group-times to land
        }

        float thrL = fmaxf(runL, waveM) - 2.0f;   // per-lane lower bound of max-2
        ull msk[16];
        int tot = 0;
#pragma unroll
        for (int j = 0; j < 16; ++j) {
            msk[j] = __ballot(z[j] > thrL);
            tot += __popcll(msk[j]);
        }
        if (tot) {
            if (n + tot > CAPW) {
                // fresh uniform wave max; evict dead entries (<= wfresh-2).
                const float wfresh = waveReduceMax(runL);
                waveM = fmaxf(waveM, wfresh);
                const float thrW = wfresh - 2.0f;
                int nn = 0;
                for (int i = 0; i < n; i += 64) {
                    const float v = (i + lane < n) ? wpool[i + lane] : -FLT_MAX;
                    const ull km = __ballot(v > thrW);
                    const int r = __popcll(km & lmask);
                    if (v > thrW) wpool[nn + r] = v;   // dest <= src: in-place safe
                    nn += __popcll(km);
                }
                n = nn;
                // re-admit this group against the tightened threshold
                thrL = fmaxf(runL, waveM) - 2.0f;
                tot = 0;
#pragma unroll
                for (int j = 0; j < 16; ++j) {
                    msk[j] = __ballot(z[j] > thrL);
                    tot += __popcll(msk[j]);
                }
            }
            if (n + tot > CAPW) {
                ovf = true;          // adversarial/degenerate rows only
            } else {
#pragma unroll
                for (int j = 0; j < 16; ++j) {
                    if (z[j] > thrL) {
                        const int r = __popcll(msk[j] & lmask);
                        wpool[n + r] = z[j];
                    }
                    n += __popcll(msk[j]);
                }
            }
        }
#pragma unroll
        for (int j = 0; j < 4; ++j) cur[j] = nxt[j];
    }
    if (ovf && lane == 0) s_flag = 1;   // benign race across waves

    if (lane == 0) s_red[wv] = waveReduceMax(runL);   // exact final wave max
    __syncthreads();
    const float max_val = fmaxf(fmaxf(s_red[0], s_red[1]), fmaxf(s_red[2], s_red[3]));
    const int flag = s_flag;
    __syncthreads();                     // s_red is reused below

    // v-space bounds: u = 2*tau.
    const float u_lo0 = max_val - 2.0f;
    const float u_hi  = max_val - 0.011180339887498949f;   // 2*(1/32000)^0.5

    if (!flag) {
        // ---- final eviction at thr = max-2 (block-uniform): pools shrink to
        // the true active superset (~600/row). Wave-local, deterministic. ----
        {
            int nn = 0;
            for (int i = 0; i < n; i += 64) {
                const float v = (i + lane < n) ? wpool[i + lane] : -FLT_MAX;
                const ull km = __ballot(v > u_lo0);
                const int r = __popcll(km & lmask);
                if (v > u_lo0) wpool[nn + r] = v;
                nn += __popcll(km);
            }
            if (lane == 0) s_cnt[wv] = nn;
        }
        __syncthreads();

        // ---- wave-0-only Newton solve over all 4 pools ----
        // g(u) = f(u) - 4 with f convex decreasing: from u_lo0, the tangent
        // step u += g / (2*S1) (S1 = sum max(v-u,0) = -f'/2) converges
        // monotonically from below; fp overshoot bounded by ~1 ulp. The max
        // element contributes exactly 4 at u_lo0 so g(u_lo0) >= 0; the
        // all-equal row roots exactly at u_hi, so the clamp is exact.
        if (wv == 0) {
            const int n0 = s_cnt[0], n1 = s_cnt[1], n2 = s_cnt[2], n3 = s_cnt[3];

#define POOL_SCAN2(uv, acc2, acc1)                                             \
            do {                                                               \
                const float* __restrict__ pp0 = s_pool;                        \
                for (int i = lane; i < n0; i += 64) {                          \
                    const float t = fmaxf(pp0[i] - (uv), 0.0f);                \
                    acc2 = fmaf(t, t, acc2); acc1 += t;                        \
                }                                                              \
                const float* __restrict__ pp1 = s_pool + CAPW;                 \
                for (int i = lane; i < n1; i += 64) {                          \
                    const float t = fmaxf(pp1[i] - (uv), 0.0f);                \
                    acc2 = fmaf(t, t, acc2); acc1 += t;                        \
                }                                                              \
                const float* __restrict__ pp2 = s_pool + 2 * CAPW;             \
                for (int i = lane; i < n2; i += 64) {                          \
                    const float t = fmaxf(pp2[i] - (uv), 0.0f);                \
                    acc2 = fmaf(t, t, acc2); acc1 += t;                        \
                }                                                              \
                const float* __restrict__ pp3 = s_pool + 3 * CAPW;             \
                for (int i = lane; i < n3; i += 64) {                          \
                    const float t = fmaxf(pp3[i] - (uv), 0.0f);                \
                    acc2 = fmaf(t, t, acc2); acc1 += t;                        \
                }                                                              \
            } while (0)

            float u = u_lo0;
            float s_v = 4.0f;
            for (int it = 0; it < 24; ++it) {
                float S2 = 0.0f, S1 = 0.0f;
                POOL_SCAN2(u, S2, S1);
                S2 = waveReduceSum(S2);
                S1 = waveReduceSum(S1);
                s_v = S2;                       // f at the CURRENT u
                const float g = S2 - 4.0f;
                if (g <= 0.0f) break;           // at/past root (<= 1 ulp past)
                const float u_new = fminf(u + g / (2.0f * S1), u_hi);
                if (u_new == u) break;          // fixpoint: root to fp32 precision
                u = u_new;
            }
#undef POOL_SCAN2
            if (lane == 0) { s_ts.x = u; s_ts.y = s_v; }
        }
        __syncthreads();   // solver result published
    } else {
        // ---- fallback (degenerate rows only): verified streaming bisection ----
        float u_lo = u_lo0;
        float acc = 0.0f;
        for (int k = 0; k < KITER; ++k) {
            const int c = threadIdx.x + k * NT;
            if (c < CHUNKS) {
                const float4 v = xr4[c];
                float t;
                t = fmaxf(v.x - u_lo, 0.0f); acc = fmaf(t, t, acc);
                t = fmaxf(v.y - u_lo, 0.0f); acc = fmaf(t, t, acc);
                t = fmaxf(v.z - u_lo, 0.0f); acc = fmaf(t, t, acc);
                t = fmaxf(v.w - u_lo, 0.0f); acc = fmaf(t, t, acc);
            }
        }
        acc = waveReduceSum(acc);
        if (lane == 0) s_red[wv] = acc;
        __syncthreads();
        const float f_lo = (s_red[0] + s_red[1] + s_red[2] + s_red[3]) - 4.0f;
        __syncthreads();

        float dm = u_hi - u_lo;
        float u_m = u_lo;
        float s_v = 4.0f;
        for (int it = 0; it < 100; ++it) {
            dm *= 0.5f;
            u_m = u_lo + dm;
            const bool fixed = (u_m == u_lo);
            float a = 0.0f;
            for (int k = 0; k < KITER; ++k) {
                const int c = threadIdx.x + k * NT;
                if (c < CHUNKS) {
                    const float4 v = xr4[c];
                    float t;
                    t = fmaxf(v.x - u_m, 0.0f); a = fmaf(t, t, a);
                    t = fmaxf(v.y - u_m, 0.0f); a = fmaf(t, t, a);
                    t = fmaxf(v.z - u_m, 0.0f); a = fmaf(t, t, a);
                    t = fmaxf(v.w - u_m, 0.0f); a = fmaf(t, t, a);
                }
            }
            a = waveReduceSum(a);
            if (lane == 0) s_red[wv] = a;
            __syncthreads();
            const float s = s_red[0] + s_red[1] + s_red[2] + s_red[3];
            __syncthreads();
            s_v = s;
            if ((s - 4.0f) * f_lo >= 0.0f) u_lo = u_m;
            if (fixed) break;
        }
        if (threadIdx.x == 0) { s_ts.x = u_m; s_ts.y = s_v; }
        __syncthreads();
    }

    // ---- epilogue: nt-load re-read (L3-hot, last use) -> log, nt-store ----
    // p = max(v-u,0)^2 * inv_sv is EXACTLY the z-space normalized probability.
    // Floor before log (DAZ-safe), bit-scrub residual inf/NaN.
    const float u_m = s_ts.x;
    const float inv_sv = 1.0f / s_ts.y;
    const f32x4* __restrict__ xv4 = reinterpret_cast<const f32x4*>(x + base);
    for (int k = 0; k < KITER; ++k) {
        const int c = threadIdx.x + k * NT;
        if (c < CHUNKS) {
            const f32x4 v = __builtin_nontemporal_load(xv4 + c);
            f32x4 o;
            {
                const float t = fmaxf(v.x - u_m, 0.0f);
                o.x = scrub_finite(__logf(fmaxf(t * t, 1e-35f) * inv_sv));
            }
            {
                const float t = fmaxf(v.y - u_m, 0.0f);
                o.y = scrub_finite(__logf(fmaxf(t * t, 1e-35f) * inv_sv));
            }
            {
                const float t = fmaxf(v.z - u_m, 0.0f);
                o.z = scrub_finite(__logf(fmaxf(t * t, 1e-35f) * inv_sv));
            }
            {
                const float t = fmaxf(v.w - u_m, 0.0f);
                o.w = scrub_finite(__logf(fmaxf(t * t, 1e-35f) * inv_sv));
            }
            __builtin_nontemporal_store(o, reinterpret_cast<f32x4*>(orow) + c);
        }
    }
}

extern "C" void kernel_launch(void* const* d_in, const int* in_sizes, int n_in,
                              void* d_out, int out_size, void* d_ws, size_t ws_size,
                              hipStream_t stream) {
    const float* x = (const float*)d_in[0];
    float* out = (float*)d_out;
    const int rows = in_sizes[0] / D_DIM;
    entmax_log_fused<<<dim3(rows), dim3(NT), 0, stream>>>(x, out, rows);
}